// Round 5
// baseline (425.699 us; speedup 1.0000x reference)
//
#include <hip/hip_runtime.h>
#include <hip/hip_fp16.h>

#define DD 128            // emb dim, fixed by problem
#define SCAN_CHUNK 1024   // elements per scan1 block
#define G_ROWS 32         // rows per gather block (8 lanes/row-half * 32 rows = 256)
#define G_STAGE 1024      // staged edges per gather block (mean 512, +22 sigma)
#define NCOPY 8           // privatized histogram copies

typedef float          f32x4 __attribute__((ext_vector_type(4)));
typedef unsigned int   u32x4 __attribute__((ext_vector_type(4)));
typedef unsigned int   u32x2 __attribute__((ext_vector_type(2)));
typedef unsigned short u16x8 __attribute__((ext_vector_type(8)));

struct __align__(8) Edge { int c; float v; };

// ---- fp16 helpers ----
__device__ __forceinline__ unsigned short f2h(float f) {
    return __half_as_ushort(__float2half(f));
}
__device__ __forceinline__ float2 up2(unsigned int u) {
    __half2 h = *reinterpret_cast<const __half2*>(&u);
    return __half22float2(h);
}

// ---- non-temporal access helpers (keep L2/L3 for the gather working set) ----
template <typename T>
__device__ __forceinline__ T ldnt(const T* p) { return __builtin_nontemporal_load(p); }
template <typename T>
__device__ __forceinline__ void stnt(T* p, T v) { __builtin_nontemporal_store(v, p); }

// ---- K1: g1 = fp16(dropout(emb,u1)) stream + ILP-4 privatized hist ---------
// Blocks [0, ceil(E/1024)) each own 1024 edges: 4 edges/thread = 4 independent
// atomic chains in flight -> amortizes the returning-atomic latency 4x.
// rank = (k<<13) | rank_within_copy  (ushort).
__global__ __launch_bounds__(256) void k_g1hist(const float* __restrict__ emb,
                                                const float* __restrict__ u1,
                                                ushort* __restrict__ g1,
                                                const int* __restrict__ rows,
                                                int* __restrict__ cnt8,
                                                ushort* __restrict__ rank,
                                                int total8, int E, int N) {
    int t = threadIdx.x;
    int b = blockIdx.x;
    int i = b * 256 + t;
    int e0 = b * 1024 + t;
    int k = b & (NCOPY - 1);
    bool doS = i < total8;

    int r[4]; bool v[4];
#pragma unroll
    for (int j = 0; j < 4; ++j) {
        int e = e0 + j * 256;
        v[j] = e < E;
        r[j] = v[j] ? ldnt(rows + e) : 0;     // 4 independent chain heads
    }
    f32x4 hA, hB, uA, uB;
    if (doS) {                                // stream loads fly under the chains
        const f32x4* e4 = (const f32x4*)emb;
        const f32x4* a4 = (const f32x4*)u1;
        hA = ldnt(e4 + 2 * (size_t)i);
        hB = ldnt(e4 + 2 * (size_t)i + 1);
        uA = ldnt(a4 + 2 * (size_t)i);
        uB = ldnt(a4 + 2 * (size_t)i + 1);
    }
    int old[4];
#pragma unroll
    for (int j = 0; j < 4; ++j)
        if (v[j]) old[j] = atomicAdd(&cnt8[(size_t)k * N + r[j]], 1);
#pragma unroll
    for (int j = 0; j < 4; ++j)
        if (v[j]) stnt(rank + e0 + j * 256, (ushort)((k << 13) | old[j]));

    if (doS) {
        const float s = 1.0f / 0.9f;
        u16x8 g;
        g[0] = f2h((uA.x >= 0.1f) ? hA.x * s : 0.0f);
        g[1] = f2h((uA.y >= 0.1f) ? hA.y * s : 0.0f);
        g[2] = f2h((uA.z >= 0.1f) ? hA.z * s : 0.0f);
        g[3] = f2h((uA.w >= 0.1f) ? hA.w * s : 0.0f);
        g[4] = f2h((uB.x >= 0.1f) ? hB.x * s : 0.0f);
        g[5] = f2h((uB.y >= 0.1f) ? hB.y * s : 0.0f);
        g[6] = f2h((uB.z >= 0.1f) ? hB.z * s : 0.0f);
        g[7] = f2h((uB.w >= 0.1f) ? hB.w * s : 0.0f);
        ((u16x8*)g1)[i] = g;   // normal store: gather1's working set
    }
}

// scan1: per row fold the NCOPY copies -> cnt8[k][r] = chunk-local rowbase +
// within-row copy offset (ABSOLUTE after scan23 adds chunk offset).
// rs[r] = chunk-local exclusive rowstart; block totals -> bsum.
__global__ __launch_bounds__(256) void k_scan1(int* __restrict__ cnt8,
                                               int* __restrict__ rs,
                                               int* __restrict__ bsum, int n) {
    __shared__ int s[256];
    int tid = threadIdx.x;
    int base = blockIdx.x * SCAN_CHUNK + tid * 4;
    int c[4][NCOPY];
    int tot[4];
#pragma unroll
    for (int j = 0; j < 4; ++j) {
        int row = base + j;
        int t = 0;
        if (row < n) {
#pragma unroll
            for (int k = 0; k < NCOPY; ++k) {
                c[j][k] = cnt8[(size_t)k * n + row];
                t += c[j][k];
            }
        }
        tot[j] = t;
    }
    int tsum = tot[0] + tot[1] + tot[2] + tot[3];
    s[tid] = tsum;
    __syncthreads();
    for (int off = 1; off < 256; off <<= 1) {
        int t = (tid >= off) ? s[tid - off] : 0;
        __syncthreads();
        s[tid] += t;
        __syncthreads();
    }
    int excl = s[tid] - tsum;
    if (tid == 255) bsum[blockIdx.x] = s[255];
    int run = excl;
#pragma unroll
    for (int j = 0; j < 4; ++j) {
        int row = base + j;
        if (row < n) {
            rs[row] = run;
            int p = run;
#pragma unroll
            for (int k = 0; k < NCOPY; ++k) {
                cnt8[(size_t)k * n + row] = p;
                p += c[j][k];
            }
        }
        run += tot[j];
    }
}

// scan23: serial prefix of bsum (nb<=1024) in LDS, then add chunk offset to
// rs AND all NCOPY cnt8 slices -> both become globally absolute.
__global__ __launch_bounds__(256) void k_scan23(int* __restrict__ rs,
                                                int* __restrict__ cnt8,
                                                const int* __restrict__ bsum,
                                                int nb, int n) {
    __shared__ int s[1024];
    int tid = threadIdx.x;
    for (int i = tid; i < nb; i += 256) s[i] = bsum[i];
    __syncthreads();
    if (tid == 0) {
        int run = 0;
        for (int i = 0; i < nb; ++i) { int t = s[i]; s[i] = run; run += t; }
    }
    __syncthreads();
    int i = blockIdx.x * 256 + tid;
    if (i < n) {
        int off = s[i >> 10];
        rs[i] += off;
#pragma unroll
        for (int k = 0; k < NCOPY; ++k) cnt8[(size_t)k * n + i] += off;
    }
}

// ---- K4: ILP-4 rank-based scatter + emb16/mask2 stream ---------------------
// pos = cnt8[k][r] + rank_in_copy : ONE random (L2-hot) load per edge, no
// atomic. 4 independent chains/thread; latency hides under the stream.
__global__ __launch_bounds__(256) void k_scatter_prep(const int* __restrict__ rows,
                                                      const int* __restrict__ cols,
                                                      const float* __restrict__ vals,
                                                      const int* __restrict__ cnt8,
                                                      const ushort* __restrict__ rank,
                                                      Edge* __restrict__ ev,
                                                      const float* __restrict__ emb,
                                                      const float* __restrict__ u2,
                                                      ushort* __restrict__ emb16,
                                                      unsigned char* __restrict__ mask2,
                                                      int E, int total8, int N) {
    int t = threadIdx.x;
    int b = blockIdx.x;
    int i = b * 256 + t;
    int e0 = b * 1024 + t;
    bool doS = i < total8;

    int r[4], c[4]; float vv[4]; unsigned int rk[4]; bool v[4];
#pragma unroll
    for (int j = 0; j < 4; ++j) {
        int e = e0 + j * 256;
        v[j] = e < E;
        if (v[j]) {
            r[j] = ldnt(rows + e);
            c[j] = ldnt(cols + e);
            vv[j] = ldnt(vals + e);
            rk[j] = ldnt(rank + e);
        }
    }
    f32x4 hA, hB, vA, vB;
    if (doS) {
        const f32x4* e4 = (const f32x4*)emb;
        const f32x4* b4 = (const f32x4*)u2;
        hA = ldnt(e4 + 2 * (size_t)i);
        hB = ldnt(e4 + 2 * (size_t)i + 1);
        vA = ldnt(b4 + 2 * (size_t)i);
        vB = ldnt(b4 + 2 * (size_t)i + 1);
    }
#pragma unroll
    for (int j = 0; j < 4; ++j) {
        if (v[j]) {
            int kk = rk[j] >> 13;
            int rin = rk[j] & 0x1FFF;
            int pos = cnt8[(size_t)kk * N + r[j]] + rin;   // hot 3.2MB, L2
            u32x2 q;
            q.x = (unsigned int)c[j];
            q.y = __float_as_uint(vv[j]);
            ((u32x2*)ev)[pos] = q;
        }
    }
    if (doS) {
        u16x8 e16;
        e16[0] = f2h(hA.x); e16[1] = f2h(hA.y); e16[2] = f2h(hA.z); e16[3] = f2h(hA.w);
        e16[4] = f2h(hB.x); e16[5] = f2h(hB.y); e16[6] = f2h(hB.z); e16[7] = f2h(hB.w);
        stnt((u16x8*)emb16 + i, e16);
        unsigned char m =
            (unsigned char)((vA.x >= 0.1f ? 1u : 0u)  | (vA.y >= 0.1f ? 2u : 0u)  |
                            (vA.z >= 0.1f ? 4u : 0u)  | (vA.w >= 0.1f ? 8u : 0u)  |
                            (vB.x >= 0.1f ? 16u : 0u) | (vB.y >= 0.1f ? 32u : 0u) |
                            (vB.z >= 0.1f ? 64u : 0u) | (vB.w >= 0.1f ? 128u : 0u));
        stnt(mask2 + i, m);
    }
}

// ---- gather SpMM, split-D -----------------------------------------------
// grid (N/32, 2): blockIdx.y picks the 64-wide D-half. x varies fastest in
// dispatch order, so the two halves run ~sequentially -> gather working set
// per phase is 12.8MB (vs 25.6), roughly doubling per-XCD L2 hit rate.
// 32 rows/block, 8 lanes/row-half, 16B loads, 8-edge unroll.
// MODE 1: p16 = fp16(h1 = A*src); g2 = fp16(dropout(h1) via mask2 bits)
// MODE 2: out = (emb16 + p16in + A*src) / 3   [fp32]
template <int MODE>
__global__ __launch_bounds__(256) void k_gather(const int* __restrict__ rowstart,
                                                const Edge* __restrict__ ev,
                                                const ushort* __restrict__ srch,
                                                const unsigned char* __restrict__ mask2,
                                                const ushort* __restrict__ emb16,
                                                const ushort* __restrict__ p16in,
                                                ushort* __restrict__ p16out,
                                                ushort* __restrict__ g2,
                                                float* __restrict__ out,
                                                int N, int E) {
    __shared__ int s_rs[G_ROWS + 1];
    __shared__ Edge s_ev[G_STAGE];

    int tid = threadIdx.x;
    int r0 = blockIdx.x * G_ROWS;
    int h = blockIdx.y;                 // D-half: halves [h*64, h*64+64)
    if (tid <= G_ROWS) {
        int r = r0 + tid;
        s_rs[tid] = (r < N) ? rowstart[r] : E;
    }
    __syncthreads();
    int base = s_rs[0];
    int nblk = s_rs[G_ROWS] - base;
    int nstage = nblk < G_STAGE ? nblk : G_STAGE;
    for (int i = tid; i < nstage; i += 256) {
        u32x2 q = ldnt((const u32x2*)(ev + base + i));
        Edge ed; ed.c = (int)q.x; ed.v = __uint_as_float(q.y);
        s_ev[i] = ed;
    }
    __syncthreads();

    int grp = tid >> 3;
    int lane = tid & 7;
    int row = r0 + grp;
    if (row >= N) return;
    int start = s_rs[grp] - base;
    int end = s_rs[grp + 1] - base;
    int eL = end < nstage ? end : nstage;

    const u32x4* __restrict__ s4 = (const u32x4*)srch;  // 16 u32x4 per row
    const Edge* __restrict__ evg = ev + base;
    int hoff = (h << 3) + lane;                          // u32x4 index in row
    float a0 = 0.f, a1 = 0.f, a2 = 0.f, a3 = 0.f;
    float a4 = 0.f, a5 = 0.f, a6 = 0.f, a7 = 0.f;

#define LDE(i) Edge E##i = s_ev[e + i];
#define GQ(i)  u32x4 q##i = s4[((size_t)E##i.c << 4) + hoff];
#define ACC(i) { float vv = E##i.v; \
        float2 w0 = up2(q##i.x), w1 = up2(q##i.y), w2 = up2(q##i.z), w3 = up2(q##i.w); \
        a0 = fmaf(vv, w0.x, a0); a1 = fmaf(vv, w0.y, a1); \
        a2 = fmaf(vv, w1.x, a2); a3 = fmaf(vv, w1.y, a3); \
        a4 = fmaf(vv, w2.x, a4); a5 = fmaf(vv, w2.y, a5); \
        a6 = fmaf(vv, w3.x, a6); a7 = fmaf(vv, w3.y, a7); }

    int e = start;
    for (; e + 8 <= eL; e += 8) {
        LDE(0) LDE(1) LDE(2) LDE(3) LDE(4) LDE(5) LDE(6) LDE(7)
        GQ(0) GQ(1) GQ(2) GQ(3) GQ(4) GQ(5) GQ(6) GQ(7)
        ACC(0) ACC(1) ACC(2) ACC(3) ACC(4) ACC(5) ACC(6) ACC(7)
    }
    if (e + 4 <= eL) {
        LDE(0) LDE(1) LDE(2) LDE(3)
        GQ(0) GQ(1) GQ(2) GQ(3)
        ACC(0) ACC(1) ACC(2) ACC(3)
        e += 4;
    }
    for (; e < eL; ++e) {
        LDE(0) GQ(0) ACC(0)
    }
    // rare spill: block had >G_STAGE edges; finish from global
    for (; e < end; ++e) {
        Edge E0; { u32x2 q_ = ldnt((const u32x2*)(evg + e));
                   E0.c = (int)q_.x; E0.v = __uint_as_float(q_.y); }
        GQ(0) ACC(0)
    }
#undef LDE
#undef GQ
#undef ACC

    size_t o = ((size_t)row << 7) + ((size_t)h << 6) + (size_t)lane * 8;
    if (MODE == 1) {
        unsigned int m = mask2[(size_t)row * 16 + (h << 3) + lane];
        const float s = 1.0f / 0.9f;
        u16x8 gg;
        gg[0] = (m & 1u)   ? f2h(a0 * s) : (ushort)0;
        gg[1] = (m & 2u)   ? f2h(a1 * s) : (ushort)0;
        gg[2] = (m & 4u)   ? f2h(a2 * s) : (ushort)0;
        gg[3] = (m & 8u)   ? f2h(a3 * s) : (ushort)0;
        gg[4] = (m & 16u)  ? f2h(a4 * s) : (ushort)0;
        gg[5] = (m & 32u)  ? f2h(a5 * s) : (ushort)0;
        gg[6] = (m & 64u)  ? f2h(a6 * s) : (ushort)0;
        gg[7] = (m & 128u) ? f2h(a7 * s) : (ushort)0;
        stnt((u16x8*)(g2 + o), gg);
        u16x8 pp;
        pp[0] = f2h(a0); pp[1] = f2h(a1); pp[2] = f2h(a2); pp[3] = f2h(a3);
        pp[4] = f2h(a4); pp[5] = f2h(a5); pp[6] = f2h(a6); pp[7] = f2h(a7);
        stnt((u16x8*)(p16out + o), pp);
    } else {
        u32x4 eq = ldnt((const u32x4*)(emb16 + o));
        u32x4 pq = ldnt((const u32x4*)(p16in + o));
        float2 e0 = up2(eq.x), e1 = up2(eq.y), e2 = up2(eq.z), e3 = up2(eq.w);
        float2 p0 = up2(pq.x), p1 = up2(pq.y), p2 = up2(pq.z), p3 = up2(pq.w);
        const float t3 = 1.0f / 3.0f;
        f32x4 rA, rB;
        rA.x = (e0.x + p0.x + a0) * t3;
        rA.y = (e0.y + p0.y + a1) * t3;
        rA.z = (e1.x + p1.x + a2) * t3;
        rA.w = (e1.y + p1.y + a3) * t3;
        rB.x = (e2.x + p2.x + a4) * t3;
        rB.y = (e2.y + p2.y + a5) * t3;
        rB.z = (e3.x + p3.x + a6) * t3;
        rB.w = (e3.y + p3.y + a7) * t3;
        stnt((f32x4*)(out + o), rA);
        stnt((f32x4*)(out + o) + 1, rB);
    }
}

// ---- launch -------------------------------------------------------------

extern "C" void kernel_launch(void* const* d_in, const int* in_sizes, int n_in,
                              void* d_out, int out_size, void* d_ws, size_t ws_size,
                              hipStream_t stream) {
    const int* rows = (const int*)d_in[1];
    const int* cols = (const int*)d_in[2];
    const float* vals = (const float*)d_in[3];
    const float* emb = (const float*)d_in[4];
    const float* u1 = (const float*)d_in[5];
    const float* u2 = (const float*)d_in[6];
    float* out = (float*)d_out;

    const int N = in_sizes[0];
    const int E = in_sizes[1];
    const size_t ND = (size_t)N * DD;

    // workspace layout (~123.6 MB)
    char* ws = (char*)d_ws;
    Edge* ev     = (Edge*)ws;   ws += (size_t)E * sizeof(Edge);        // 12.8MB
    ushort* g1   = (ushort*)ws; ws += ND * sizeof(ushort);             // 25.6MB fp16
    ushort* g2   = (ushort*)ws; ws += ND * sizeof(ushort);             // 25.6MB fp16
    ushort* p16  = (ushort*)ws; ws += ND * sizeof(ushort);             // 25.6MB fp16 h1
    ushort* emb16= (ushort*)ws; ws += ND * sizeof(ushort);             // 25.6MB fp16 emb
    int* cnt8    = (int*)ws;    ws += (size_t)NCOPY * N * sizeof(int); // 3.2MB
    int* rs      = (int*)ws;    ws += (size_t)N * sizeof(int);         // 0.4MB rowstart
    ushort* rank = (ushort*)ws; ws += (size_t)E * sizeof(ushort);      // 3.2MB
    int* bsum    = (int*)ws;    ws += 4096;
    unsigned char* mask2 = (unsigned char*)ws;                         // 1.6MB

    const int total8 = (int)(ND / 8);
    const int prepBlocks = (total8 + 255) / 256;
    const int gridE = (E + 1023) / 1024;        // ILP-4 edge blocks
    const int gridFuse = prepBlocks > gridE ? prepBlocks : gridE;
    const int nScanBlocks = (N + SCAN_CHUNK - 1) / SCAN_CHUNK;
    const int gridRowX = (N + G_ROWS - 1) / G_ROWS;
    dim3 gridRow(gridRowX, 2, 1);

    hipMemsetAsync(cnt8, 0, (size_t)NCOPY * N * sizeof(int), stream);
    // g1 stream + ILP-4 privatized hist
    k_g1hist<<<gridFuse, 256, 0, stream>>>(emb, u1, g1, rows, cnt8, rank,
                                           total8, E, N);
    k_scan1<<<nScanBlocks, 256, 0, stream>>>(cnt8, rs, bsum, N);
    k_scan23<<<(N + 255) / 256, 256, 0, stream>>>(rs, cnt8, bsum, nScanBlocks, N);
    // ILP-4 single-lookup scatter + emb16/mask2 stream
    k_scatter_prep<<<gridFuse, 256, 0, stream>>>(rows, cols, vals, cnt8, rank,
                                                 ev, emb, u2, emb16, mask2,
                                                 E, total8, N);
    // h1 = A*g1; p16 = fp16(h1); g2 = fp16(dropout(h1, mask2))
    k_gather<1><<<gridRow, 256, 0, stream>>>(rs, ev, g1, mask2, nullptr, nullptr,
                                             p16, g2, nullptr, N, E);
    // out = (emb16 + p16 + A*g2)/3
    k_gather<2><<<gridRow, 256, 0, stream>>>(rs, ev, g2, nullptr, emb16, p16,
                                             nullptr, nullptr, out, N, E);
}

// Round 6
// 403.659 us; speedup vs baseline: 1.0546x; 1.0546x over previous
//
#include <hip/hip_runtime.h>
#include <hip/hip_fp16.h>

#define DD 128            // emb dim, fixed by problem
#define SCAN_CHUNK 1024   // elements per scan1 block
#define G_ROWS 32         // rows per gather block (8 lanes/row-half * 32 rows = 256)
#define G_STAGE 1024      // staged edges per gather block (mean 512, +22 sigma)
#define NCOPY 8           // privatized histogram copies

typedef float          f32x4 __attribute__((ext_vector_type(4)));
typedef unsigned int   u32x4 __attribute__((ext_vector_type(4)));
typedef unsigned int   u32x2 __attribute__((ext_vector_type(2)));
typedef unsigned short u16x8 __attribute__((ext_vector_type(8)));

struct __align__(8) Edge { int c; float v; };

// ---- fp16 helpers ----
__device__ __forceinline__ unsigned short f2h(float f) {
    return __half_as_ushort(__float2half(f));
}
__device__ __forceinline__ float2 up2(unsigned int u) {
    __half2 h = *reinterpret_cast<const __half2*>(&u);
    return __half22float2(h);
}

// ---- non-temporal access helpers (keep L2/L3 for the gather working set) ----
template <typename T>
__device__ __forceinline__ T ldnt(const T* p) { return __builtin_nontemporal_load(p); }
template <typename T>
__device__ __forceinline__ void stnt(T* p, T v) { __builtin_nontemporal_store(v, p); }

// ---- K1: g1 = fp16(dropout(emb,u1)) stream + 1-edge/thread privatized hist -
// Edge work spread evenly over ALL streaming blocks (round-5 lesson: ILP-4
// concentration created a latency tail). Copy k = blockIdx&7; atomic chain
// hides under the stream loads. rank = (k<<13) | rank_within_copy (ushort).
__global__ __launch_bounds__(256) void k_g1hist(const float* __restrict__ emb,
                                                const float* __restrict__ u1,
                                                ushort* __restrict__ g1,
                                                const int* __restrict__ rows,
                                                int* __restrict__ cnt8,
                                                ushort* __restrict__ rank,
                                                int total8, int E, int N) {
    int i = blockIdx.x * 256 + threadIdx.x;
    int k = blockIdx.x & (NCOPY - 1);
    bool doE = i < E;
    bool doS = i < total8;
    int r = 0;
    if (doE) r = ldnt(rows + i);            // chain head issues first
    f32x4 hA, hB, uA, uB;
    if (doS) {                              // stream loads fly under the chain
        const f32x4* e4 = (const f32x4*)emb;
        const f32x4* a4 = (const f32x4*)u1;
        hA = ldnt(e4 + 2 * (size_t)i);
        hB = ldnt(e4 + 2 * (size_t)i + 1);
        uA = ldnt(a4 + 2 * (size_t)i);
        uB = ldnt(a4 + 2 * (size_t)i + 1);
    }
    if (doE) {
        int old = atomicAdd(&cnt8[(size_t)k * N + r], 1);
        stnt(rank + i, (ushort)((k << 13) | old));
    }
    if (doS) {
        const float s = 1.0f / 0.9f;
        u16x8 g;
        g[0] = f2h((uA.x >= 0.1f) ? hA.x * s : 0.0f);
        g[1] = f2h((uA.y >= 0.1f) ? hA.y * s : 0.0f);
        g[2] = f2h((uA.z >= 0.1f) ? hA.z * s : 0.0f);
        g[3] = f2h((uA.w >= 0.1f) ? hA.w * s : 0.0f);
        g[4] = f2h((uB.x >= 0.1f) ? hB.x * s : 0.0f);
        g[5] = f2h((uB.y >= 0.1f) ? hB.y * s : 0.0f);
        g[6] = f2h((uB.z >= 0.1f) ? hB.z * s : 0.0f);
        g[7] = f2h((uB.w >= 0.1f) ? hB.w * s : 0.0f);
        ((u16x8*)g1)[i] = g;   // normal store: gather1's working set
    }
}

// scan1: per row fold the NCOPY copies -> cnt8[k][r] = chunk-local rowbase +
// within-row copy offset (ABSOLUTE after scan23 adds chunk offset).
// rs[r] = chunk-local exclusive rowstart; block totals -> bsum.
__global__ __launch_bounds__(256) void k_scan1(int* __restrict__ cnt8,
                                               int* __restrict__ rs,
                                               int* __restrict__ bsum, int n) {
    __shared__ int s[256];
    int tid = threadIdx.x;
    int base = blockIdx.x * SCAN_CHUNK + tid * 4;
    int c[4][NCOPY];
    int tot[4];
#pragma unroll
    for (int j = 0; j < 4; ++j) {
        int row = base + j;
        int t = 0;
        if (row < n) {
#pragma unroll
            for (int k = 0; k < NCOPY; ++k) {
                c[j][k] = cnt8[(size_t)k * n + row];
                t += c[j][k];
            }
        }
        tot[j] = t;
    }
    int tsum = tot[0] + tot[1] + tot[2] + tot[3];
    s[tid] = tsum;
    __syncthreads();
    for (int off = 1; off < 256; off <<= 1) {
        int t = (tid >= off) ? s[tid - off] : 0;
        __syncthreads();
        s[tid] += t;
        __syncthreads();
    }
    int excl = s[tid] - tsum;
    if (tid == 255) bsum[blockIdx.x] = s[255];
    int run = excl;
#pragma unroll
    for (int j = 0; j < 4; ++j) {
        int row = base + j;
        if (row < n) {
            rs[row] = run;
            int p = run;
#pragma unroll
            for (int k = 0; k < NCOPY; ++k) {
                cnt8[(size_t)k * n + row] = p;
                p += c[j][k];
            }
        }
        run += tot[j];
    }
}

// scan23: serial prefix of bsum (nb<=1024) in LDS, then add chunk offset to
// rs AND all NCOPY cnt8 slices -> both become globally absolute.
__global__ __launch_bounds__(256) void k_scan23(int* __restrict__ rs,
                                                int* __restrict__ cnt8,
                                                const int* __restrict__ bsum,
                                                int nb, int n) {
    __shared__ int s[1024];
    int tid = threadIdx.x;
    for (int i = tid; i < nb; i += 256) s[i] = bsum[i];
    __syncthreads();
    if (tid == 0) {
        int run = 0;
        for (int i = 0; i < nb; ++i) { int t = s[i]; s[i] = run; run += t; }
    }
    __syncthreads();
    int i = blockIdx.x * 256 + tid;
    if (i < n) {
        int off = s[i >> 10];
        rs[i] += off;
#pragma unroll
        for (int k = 0; k < NCOPY; ++k) cnt8[(size_t)k * n + i] += off;
    }
}

// ---- K4: 1-edge/thread single-lookup scatter + emb16/mask2 stream ----------
// pos = cnt8[k][r] + rank_in_copy : ONE random (L2-hot) load per edge, no
// atomic. Latency hides under the stream in the same wave.
__global__ __launch_bounds__(256) void k_scatter_prep(const int* __restrict__ rows,
                                                      const int* __restrict__ cols,
                                                      const float* __restrict__ vals,
                                                      const int* __restrict__ cnt8,
                                                      const ushort* __restrict__ rank,
                                                      Edge* __restrict__ ev,
                                                      const float* __restrict__ emb,
                                                      const float* __restrict__ u2,
                                                      ushort* __restrict__ emb16,
                                                      unsigned char* __restrict__ mask2,
                                                      int E, int total8, int N) {
    int i = blockIdx.x * 256 + threadIdx.x;
    bool doE = i < E;
    bool doS = i < total8;
    int r = 0, c = 0; float vv = 0.f; unsigned int rk = 0;
    if (doE) {
        r = ldnt(rows + i);
        c = ldnt(cols + i);
        vv = ldnt(vals + i);
        rk = ldnt(rank + i);
    }
    f32x4 hA, hB, vA, vB;
    if (doS) {
        const f32x4* e4 = (const f32x4*)emb;
        const f32x4* b4 = (const f32x4*)u2;
        hA = ldnt(e4 + 2 * (size_t)i);
        hB = ldnt(e4 + 2 * (size_t)i + 1);
        vA = ldnt(b4 + 2 * (size_t)i);
        vB = ldnt(b4 + 2 * (size_t)i + 1);
    }
    if (doE) {
        int kk = rk >> 13;
        int rin = rk & 0x1FFF;
        int pos = cnt8[(size_t)kk * N + r] + rin;   // hot 3.2MB, L2
        u32x2 q;
        q.x = (unsigned int)c;
        q.y = __float_as_uint(vv);
        ((u32x2*)ev)[pos] = q;        // normal store: L2/L3 absorbs amplification
    }
    if (doS) {
        u16x8 e16;
        e16[0] = f2h(hA.x); e16[1] = f2h(hA.y); e16[2] = f2h(hA.z); e16[3] = f2h(hA.w);
        e16[4] = f2h(hB.x); e16[5] = f2h(hB.y); e16[6] = f2h(hB.z); e16[7] = f2h(hB.w);
        stnt((u16x8*)emb16 + i, e16);
        unsigned char m =
            (unsigned char)((vA.x >= 0.1f ? 1u : 0u)  | (vA.y >= 0.1f ? 2u : 0u)  |
                            (vA.z >= 0.1f ? 4u : 0u)  | (vA.w >= 0.1f ? 8u : 0u)  |
                            (vB.x >= 0.1f ? 16u : 0u) | (vB.y >= 0.1f ? 32u : 0u) |
                            (vB.z >= 0.1f ? 64u : 0u) | (vB.w >= 0.1f ? 128u : 0u));
        stnt(mask2 + i, m);
    }
}

// ---- gather SpMM, split-D -----------------------------------------------
// grid (N/32, 2): blockIdx.y picks the 64-wide D-half (halved working set).
// 32 rows/block, 8 lanes/row-half, 16B loads. 8-edge batches; the remainder
// (avg ~3.5 edges) is ONE PREDICATED 8-batch (clamped index, zeroed
// multiplier) instead of a serial 1-load chain: tail latency 7 rounds -> 1.
// MODE 1: p16 = fp16(h1 = A*src); g2 = fp16(dropout(h1) via mask2 bits)
// MODE 2: out = (emb16 + p16in + A*src) / 3   [fp32]
template <int MODE>
__global__ __launch_bounds__(256) void k_gather(const int* __restrict__ rowstart,
                                                const Edge* __restrict__ ev,
                                                const ushort* __restrict__ srch,
                                                const unsigned char* __restrict__ mask2,
                                                const ushort* __restrict__ emb16,
                                                const ushort* __restrict__ p16in,
                                                ushort* __restrict__ p16out,
                                                ushort* __restrict__ g2,
                                                float* __restrict__ out,
                                                int N, int E) {
    __shared__ int s_rs[G_ROWS + 1];
    __shared__ Edge s_ev[G_STAGE];

    int tid = threadIdx.x;
    int r0 = blockIdx.x * G_ROWS;
    int h = blockIdx.y;                 // D-half: halves [h*64, h*64+64)
    if (tid <= G_ROWS) {
        int r = r0 + tid;
        s_rs[tid] = (r < N) ? rowstart[r] : E;
    }
    __syncthreads();
    int base = s_rs[0];
    int nblk = s_rs[G_ROWS] - base;
    int nstage = nblk < G_STAGE ? nblk : G_STAGE;
    for (int i = tid; i < nstage; i += 256) {
        u32x2 q = ldnt((const u32x2*)(ev + base + i));
        Edge ed; ed.c = (int)q.x; ed.v = __uint_as_float(q.y);
        s_ev[i] = ed;
    }
    __syncthreads();

    int grp = tid >> 3;
    int lane = tid & 7;
    int row = r0 + grp;
    if (row >= N) return;
    int start = s_rs[grp] - base;
    int end = s_rs[grp + 1] - base;
    int eL = end < nstage ? end : nstage;

    const u32x4* __restrict__ s4 = (const u32x4*)srch;  // 16 u32x4 per row
    const Edge* __restrict__ evg = ev + base;
    int hoff = (h << 3) + lane;                          // u32x4 index in row
    float a0 = 0.f, a1 = 0.f, a2 = 0.f, a3 = 0.f;
    float a4 = 0.f, a5 = 0.f, a6 = 0.f, a7 = 0.f;

#define LDE(i) Edge E##i = s_ev[e + i]; float fv##i = E##i.v;
#define LDP(i) int ix##i = e + i; bool ok##i = ix##i < eL; \
               Edge E##i = s_ev[ok##i ? ix##i : last]; \
               float fv##i = ok##i ? E##i.v : 0.0f;
#define GQ(i)  u32x4 q##i = s4[((size_t)E##i.c << 4) + hoff];
#define ACC(i) { float vv = fv##i; \
        float2 w0 = up2(q##i.x), w1 = up2(q##i.y), w2 = up2(q##i.z), w3 = up2(q##i.w); \
        a0 = fmaf(vv, w0.x, a0); a1 = fmaf(vv, w0.y, a1); \
        a2 = fmaf(vv, w1.x, a2); a3 = fmaf(vv, w1.y, a3); \
        a4 = fmaf(vv, w2.x, a4); a5 = fmaf(vv, w2.y, a5); \
        a6 = fmaf(vv, w3.x, a6); a7 = fmaf(vv, w3.y, a7); }

    int e = start;
    for (; e + 8 <= eL; e += 8) {
        LDE(0) LDE(1) LDE(2) LDE(3) LDE(4) LDE(5) LDE(6) LDE(7)
        GQ(0) GQ(1) GQ(2) GQ(3) GQ(4) GQ(5) GQ(6) GQ(7)
        ACC(0) ACC(1) ACC(2) ACC(3) ACC(4) ACC(5) ACC(6) ACC(7)
    }
    if (e < eL) {   // predicated 8-batch covers remainder 1..7 in ONE round
        int last = eL - 1;
        LDP(0) LDP(1) LDP(2) LDP(3) LDP(4) LDP(5) LDP(6) LDP(7)
        GQ(0) GQ(1) GQ(2) GQ(3) GQ(4) GQ(5) GQ(6) GQ(7)
        ACC(0) ACC(1) ACC(2) ACC(3) ACC(4) ACC(5) ACC(6) ACC(7)
        e = eL;
    }
    // rare spill: block had >G_STAGE edges; finish from global
    for (; e < end; ++e) {
        Edge E0; { u32x2 q_ = ldnt((const u32x2*)(evg + e));
                   E0.c = (int)q_.x; E0.v = __uint_as_float(q_.y); }
        float fv0 = E0.v;
        GQ(0) ACC(0)
    }
#undef LDE
#undef LDP
#undef GQ
#undef ACC

    size_t o = ((size_t)row << 7) + ((size_t)h << 6) + (size_t)lane * 8;
    if (MODE == 1) {
        unsigned int m = mask2[(size_t)row * 16 + (h << 3) + lane];
        const float s = 1.0f / 0.9f;
        u16x8 gg;
        gg[0] = (m & 1u)   ? f2h(a0 * s) : (ushort)0;
        gg[1] = (m & 2u)   ? f2h(a1 * s) : (ushort)0;
        gg[2] = (m & 4u)   ? f2h(a2 * s) : (ushort)0;
        gg[3] = (m & 8u)   ? f2h(a3 * s) : (ushort)0;
        gg[4] = (m & 16u)  ? f2h(a4 * s) : (ushort)0;
        gg[5] = (m & 32u)  ? f2h(a5 * s) : (ushort)0;
        gg[6] = (m & 64u)  ? f2h(a6 * s) : (ushort)0;
        gg[7] = (m & 128u) ? f2h(a7 * s) : (ushort)0;
        stnt((u16x8*)(g2 + o), gg);
        u16x8 pp;
        pp[0] = f2h(a0); pp[1] = f2h(a1); pp[2] = f2h(a2); pp[3] = f2h(a3);
        pp[4] = f2h(a4); pp[5] = f2h(a5); pp[6] = f2h(a6); pp[7] = f2h(a7);
        stnt((u16x8*)(p16out + o), pp);
    } else {
        u32x4 eq = ldnt((const u32x4*)(emb16 + o));
        u32x4 pq = ldnt((const u32x4*)(p16in + o));
        float2 e0 = up2(eq.x), e1 = up2(eq.y), e2 = up2(eq.z), e3 = up2(eq.w);
        float2 p0 = up2(pq.x), p1 = up2(pq.y), p2 = up2(pq.z), p3 = up2(pq.w);
        const float t3 = 1.0f / 3.0f;
        f32x4 rA, rB;
        rA.x = (e0.x + p0.x + a0) * t3;
        rA.y = (e0.y + p0.y + a1) * t3;
        rA.z = (e1.x + p1.x + a2) * t3;
        rA.w = (e1.y + p1.y + a3) * t3;
        rB.x = (e2.x + p2.x + a4) * t3;
        rB.y = (e2.y + p2.y + a5) * t3;
        rB.z = (e3.x + p3.x + a6) * t3;
        rB.w = (e3.y + p3.y + a7) * t3;
        stnt((f32x4*)(out + o), rA);
        stnt((f32x4*)(out + o) + 1, rB);
    }
}

// ---- launch -------------------------------------------------------------

extern "C" void kernel_launch(void* const* d_in, const int* in_sizes, int n_in,
                              void* d_out, int out_size, void* d_ws, size_t ws_size,
                              hipStream_t stream) {
    const int* rows = (const int*)d_in[1];
    const int* cols = (const int*)d_in[2];
    const float* vals = (const float*)d_in[3];
    const float* emb = (const float*)d_in[4];
    const float* u1 = (const float*)d_in[5];
    const float* u2 = (const float*)d_in[6];
    float* out = (float*)d_out;

    const int N = in_sizes[0];
    const int E = in_sizes[1];
    const size_t ND = (size_t)N * DD;

    // workspace layout (~123.6 MB)
    char* ws = (char*)d_ws;
    Edge* ev     = (Edge*)ws;   ws += (size_t)E * sizeof(Edge);        // 12.8MB
    ushort* g1   = (ushort*)ws; ws += ND * sizeof(ushort);             // 25.6MB fp16
    ushort* g2   = (ushort*)ws; ws += ND * sizeof(ushort);             // 25.6MB fp16
    ushort* p16  = (ushort*)ws; ws += ND * sizeof(ushort);             // 25.6MB fp16 h1
    ushort* emb16= (ushort*)ws; ws += ND * sizeof(ushort);             // 25.6MB fp16 emb
    int* cnt8    = (int*)ws;    ws += (size_t)NCOPY * N * sizeof(int); // 3.2MB
    int* rs      = (int*)ws;    ws += (size_t)N * sizeof(int);         // 0.4MB rowstart
    ushort* rank = (ushort*)ws; ws += (size_t)E * sizeof(ushort);      // 3.2MB
    int* bsum    = (int*)ws;    ws += 4096;
    unsigned char* mask2 = (unsigned char*)ws;                         // 1.6MB

    const int total8 = (int)(ND / 8);
    const int prepBlocks = (total8 + 255) / 256;
    const int gridE = (E + 255) / 256;
    const int gridFuse = prepBlocks > gridE ? prepBlocks : gridE;
    const int nScanBlocks = (N + SCAN_CHUNK - 1) / SCAN_CHUNK;
    const int gridRowX = (N + G_ROWS - 1) / G_ROWS;
    dim3 gridRow(gridRowX, 2, 1);

    hipMemsetAsync(cnt8, 0, (size_t)NCOPY * N * sizeof(int), stream);
    // g1 stream + 1-edge/thread privatized hist
    k_g1hist<<<gridFuse, 256, 0, stream>>>(emb, u1, g1, rows, cnt8, rank,
                                           total8, E, N);
    k_scan1<<<nScanBlocks, 256, 0, stream>>>(cnt8, rs, bsum, N);
    k_scan23<<<(N + 255) / 256, 256, 0, stream>>>(rs, cnt8, bsum, nScanBlocks, N);
    // 1-edge/thread single-lookup scatter + emb16/mask2 stream
    k_scatter_prep<<<gridFuse, 256, 0, stream>>>(rows, cols, vals, cnt8, rank,
                                                 ev, emb, u2, emb16, mask2,
                                                 E, total8, N);
    // h1 = A*g1; p16 = fp16(h1); g2 = fp16(dropout(h1, mask2))
    k_gather<1><<<gridRow, 256, 0, stream>>>(rs, ev, g1, mask2, nullptr, nullptr,
                                             p16, g2, nullptr, N, E);
    // out = (emb16 + p16 + A*g2)/3
    k_gather<2><<<gridRow, 256, 0, stream>>>(rs, ev, g2, nullptr, emb16, p16,
                                             nullptr, nullptr, out, N, E);
}

// Round 7
// 403.354 us; speedup vs baseline: 1.0554x; 1.0008x over previous
//
#include <hip/hip_runtime.h>
#include <hip/hip_fp16.h>

#define DD 128            // emb dim, fixed by problem
#define SCAN_CHUNK 1024   // rows per scan1 block
#define G_ROWS 32         // rows per gather block (8 lanes/row-half * 32 rows = 256)
#define G_STAGE 1024      // staged edges per gather block (mean 512, +22 sigma)

typedef float          f32x4 __attribute__((ext_vector_type(4)));
typedef unsigned int   u32x4 __attribute__((ext_vector_type(4)));
typedef unsigned int   u32x2 __attribute__((ext_vector_type(2)));
typedef unsigned short u16x8 __attribute__((ext_vector_type(8)));

struct __align__(8) Edge { int c; float v; };

// ---- fp16 helpers ----
__device__ __forceinline__ unsigned short f2h(float f) {
    return __half_as_ushort(__float2half(f));
}
__device__ __forceinline__ float2 up2(unsigned int u) {
    __half2 h = *reinterpret_cast<const __half2*>(&u);
    return __half22float2(h);
}

// ---- non-temporal access helpers (keep L2/L3 for the gather working set) ----
template <typename T>
__device__ __forceinline__ T ldnt(const T* p) { return __builtin_nontemporal_load(p); }
template <typename T>
__device__ __forceinline__ void stnt(T* p, T v) { __builtin_nontemporal_store(v, p); }

// ---- K1: g1 = fp16(dropout(emb,u1)) stream + packed-16b hist ---------------
// Counters: 2 rows per 32-bit word -> 200KB total footprint (3125 lines).
// Device-scope atomics resolve at the memory-side coherence point at LINE
// granularity; shrinking lines 16x shrinks the atomic traffic surcharge.
// Per-row count <= ~50 << 2^16: no cross-field carry. rank = old field.
__global__ __launch_bounds__(256) void k_g1hist(const float* __restrict__ emb,
                                                const float* __restrict__ u1,
                                                ushort* __restrict__ g1,
                                                const int* __restrict__ rows,
                                                unsigned int* __restrict__ cnt16,
                                                ushort* __restrict__ rank,
                                                int total8, int E) {
    int i = blockIdx.x * 256 + threadIdx.x;
    bool doE = i < E;
    bool doS = i < total8;
    int r = 0;
    if (doE) r = ldnt(rows + i);            // chain head issues first
    f32x4 hA, hB, uA, uB;
    if (doS) {                              // stream loads fly under the chain
        const f32x4* e4 = (const f32x4*)emb;
        const f32x4* a4 = (const f32x4*)u1;
        hA = ldnt(e4 + 2 * (size_t)i);
        hB = ldnt(e4 + 2 * (size_t)i + 1);
        uA = ldnt(a4 + 2 * (size_t)i);
        uB = ldnt(a4 + 2 * (size_t)i + 1);
    }
    if (doE) {
        int sh = (r & 1) << 4;
        unsigned int old = atomicAdd(&cnt16[r >> 1], 1u << sh);
        stnt(rank + i, (ushort)((old >> sh) & 0xFFFFu));
    }
    if (doS) {
        const float s = 1.0f / 0.9f;
        u16x8 g;
        g[0] = f2h((uA.x >= 0.1f) ? hA.x * s : 0.0f);
        g[1] = f2h((uA.y >= 0.1f) ? hA.y * s : 0.0f);
        g[2] = f2h((uA.z >= 0.1f) ? hA.z * s : 0.0f);
        g[3] = f2h((uA.w >= 0.1f) ? hA.w * s : 0.0f);
        g[4] = f2h((uB.x >= 0.1f) ? hB.x * s : 0.0f);
        g[5] = f2h((uB.y >= 0.1f) ? hB.y * s : 0.0f);
        g[6] = f2h((uB.z >= 0.1f) ? hB.z * s : 0.0f);
        g[7] = f2h((uB.w >= 0.1f) ? hB.w * s : 0.0f);
        ((u16x8*)g1)[i] = g;   // normal store: gather1's working set
    }
}

// scan1: read packed counters (200KB), per-thread 4 rows (2 words), block
// exclusive scan -> rs (chunk-local exclusive rowstart), block totals -> bsum.
__global__ __launch_bounds__(256) void k_scan1(const unsigned int* __restrict__ cnt16,
                                               int* __restrict__ rs,
                                               int* __restrict__ bsum, int n) {
    __shared__ int s[256];
    int tid = threadIdx.x;
    int base = blockIdx.x * SCAN_CHUNK + tid * 4;   // even
    int c0 = 0, c1 = 0, c2 = 0, c3 = 0;
    if (base < n) {                                  // n even: base+1 valid too
        unsigned int w0 = cnt16[base >> 1];
        c0 = (int)(w0 & 0xFFFFu);
        c1 = (int)(w0 >> 16);
    }
    if (base + 2 < n) {
        unsigned int w1 = cnt16[(base >> 1) + 1];
        c2 = (int)(w1 & 0xFFFFu);
        c3 = (int)(w1 >> 16);
    }
    int tsum = c0 + c1 + c2 + c3;
    s[tid] = tsum;
    __syncthreads();
    for (int off = 1; off < 256; off <<= 1) {
        int t = (tid >= off) ? s[tid - off] : 0;
        __syncthreads();
        s[tid] += t;
        __syncthreads();
    }
    int excl = s[tid] - tsum;
    if (tid == 255) bsum[blockIdx.x] = s[255];
    if (base < n)     rs[base]     = excl;
    if (base + 1 < n) rs[base + 1] = excl + c0;
    if (base + 2 < n) rs[base + 2] = excl + c0 + c1;
    if (base + 3 < n) rs[base + 3] = excl + c0 + c1 + c2;
}

// scan23: serial prefix of bsum (nb<=1024) in LDS, add chunk offset to rs.
// rs becomes the global rowstart.
__global__ __launch_bounds__(256) void k_scan23(int* __restrict__ rs,
                                                const int* __restrict__ bsum,
                                                int nb, int n) {
    __shared__ int s[1024];
    int tid = threadIdx.x;
    for (int i = tid; i < nb; i += 256) s[i] = bsum[i];
    __syncthreads();
    if (tid == 0) {
        int run = 0;
        for (int i = 0; i < nb; ++i) { int t = s[i]; s[i] = run; run += t; }
    }
    __syncthreads();
    int i = blockIdx.x * 256 + tid;
    if (i < n) rs[i] += s[i >> 10];
}

// ---- K4: 1-edge/thread scatter + emb16/mask2 stream ------------------------
// pos = rs[r] + rank[e] : ONE random (L2-hot, 400KB) load per edge, no
// atomic. Latency hides under the stream in the same wave.
__global__ __launch_bounds__(256) void k_scatter_prep(const int* __restrict__ rows,
                                                      const int* __restrict__ cols,
                                                      const float* __restrict__ vals,
                                                      const int* __restrict__ rs,
                                                      const ushort* __restrict__ rank,
                                                      Edge* __restrict__ ev,
                                                      const float* __restrict__ emb,
                                                      const float* __restrict__ u2,
                                                      ushort* __restrict__ emb16,
                                                      unsigned char* __restrict__ mask2,
                                                      int E, int total8) {
    int i = blockIdx.x * 256 + threadIdx.x;
    bool doE = i < E;
    bool doS = i < total8;
    int r = 0, c = 0; float vv = 0.f; unsigned int rk = 0;
    if (doE) {
        r = ldnt(rows + i);
        c = ldnt(cols + i);
        vv = ldnt(vals + i);
        rk = ldnt(rank + i);
    }
    f32x4 hA, hB, vA, vB;
    if (doS) {
        const f32x4* e4 = (const f32x4*)emb;
        const f32x4* b4 = (const f32x4*)u2;
        hA = ldnt(e4 + 2 * (size_t)i);
        hB = ldnt(e4 + 2 * (size_t)i + 1);
        vA = ldnt(b4 + 2 * (size_t)i);
        vB = ldnt(b4 + 2 * (size_t)i + 1);
    }
    if (doE) {
        int pos = rs[r] + (int)rk;    // hot 400KB, L2
        u32x2 q;
        q.x = (unsigned int)c;
        q.y = __float_as_uint(vv);
        ((u32x2*)ev)[pos] = q;        // normal store: L2/L3 absorbs amplification
    }
    if (doS) {
        u16x8 e16;
        e16[0] = f2h(hA.x); e16[1] = f2h(hA.y); e16[2] = f2h(hA.z); e16[3] = f2h(hA.w);
        e16[4] = f2h(hB.x); e16[5] = f2h(hB.y); e16[6] = f2h(hB.z); e16[7] = f2h(hB.w);
        stnt((u16x8*)emb16 + i, e16);
        unsigned char m =
            (unsigned char)((vA.x >= 0.1f ? 1u : 0u)  | (vA.y >= 0.1f ? 2u : 0u)  |
                            (vA.z >= 0.1f ? 4u : 0u)  | (vA.w >= 0.1f ? 8u : 0u)  |
                            (vB.x >= 0.1f ? 16u : 0u) | (vB.y >= 0.1f ? 32u : 0u) |
                            (vB.z >= 0.1f ? 64u : 0u) | (vB.w >= 0.1f ? 128u : 0u));
        stnt(mask2 + i, m);
    }
}

// ---- gather SpMM, split-D -----------------------------------------------
// grid (N/32, 2): blockIdx.y picks the 64-wide D-half (halved working set).
// 32 rows/block, 8 lanes/row-half, 16B loads. 8-edge batches; remainder is
// ONE PREDICATED 8-batch (clamped index, zeroed multiplier).
// MODE 1: p16 = fp16(h1 = A*src); g2 = fp16(dropout(h1) via mask2 bits)
// MODE 2: out = (emb16 + p16in + A*src) / 3   [fp32]
template <int MODE>
__global__ __launch_bounds__(256) void k_gather(const int* __restrict__ rowstart,
                                                const Edge* __restrict__ ev,
                                                const ushort* __restrict__ srch,
                                                const unsigned char* __restrict__ mask2,
                                                const ushort* __restrict__ emb16,
                                                const ushort* __restrict__ p16in,
                                                ushort* __restrict__ p16out,
                                                ushort* __restrict__ g2,
                                                float* __restrict__ out,
                                                int N, int E) {
    __shared__ int s_rs[G_ROWS + 1];
    __shared__ Edge s_ev[G_STAGE];

    int tid = threadIdx.x;
    int r0 = blockIdx.x * G_ROWS;
    int h = blockIdx.y;                 // D-half: halves [h*64, h*64+64)
    if (tid <= G_ROWS) {
        int r = r0 + tid;
        s_rs[tid] = (r < N) ? rowstart[r] : E;
    }
    __syncthreads();
    int base = s_rs[0];
    int nblk = s_rs[G_ROWS] - base;
    int nstage = nblk < G_STAGE ? nblk : G_STAGE;
    for (int i = tid; i < nstage; i += 256) {
        u32x2 q = ldnt((const u32x2*)(ev + base + i));
        Edge ed; ed.c = (int)q.x; ed.v = __uint_as_float(q.y);
        s_ev[i] = ed;
    }
    __syncthreads();

    int grp = tid >> 3;
    int lane = tid & 7;
    int row = r0 + grp;
    if (row >= N) return;
    int start = s_rs[grp] - base;
    int end = s_rs[grp + 1] - base;
    int eL = end < nstage ? end : nstage;

    const u32x4* __restrict__ s4 = (const u32x4*)srch;  // 16 u32x4 per row
    const Edge* __restrict__ evg = ev + base;
    int hoff = (h << 3) + lane;                          // u32x4 index in row
    float a0 = 0.f, a1 = 0.f, a2 = 0.f, a3 = 0.f;
    float a4 = 0.f, a5 = 0.f, a6 = 0.f, a7 = 0.f;

#define LDE(i) Edge E##i = s_ev[e + i]; float fv##i = E##i.v;
#define LDP(i) int ix##i = e + i; bool ok##i = ix##i < eL; \
               Edge E##i = s_ev[ok##i ? ix##i : last]; \
               float fv##i = ok##i ? E##i.v : 0.0f;
#define GQ(i)  u32x4 q##i = s4[((size_t)E##i.c << 4) + hoff];
#define ACC(i) { float vv = fv##i; \
        float2 w0 = up2(q##i.x), w1 = up2(q##i.y), w2 = up2(q##i.z), w3 = up2(q##i.w); \
        a0 = fmaf(vv, w0.x, a0); a1 = fmaf(vv, w0.y, a1); \
        a2 = fmaf(vv, w1.x, a2); a3 = fmaf(vv, w1.y, a3); \
        a4 = fmaf(vv, w2.x, a4); a5 = fmaf(vv, w2.y, a5); \
        a6 = fmaf(vv, w3.x, a6); a7 = fmaf(vv, w3.y, a7); }

    int e = start;
    for (; e + 8 <= eL; e += 8) {
        LDE(0) LDE(1) LDE(2) LDE(3) LDE(4) LDE(5) LDE(6) LDE(7)
        GQ(0) GQ(1) GQ(2) GQ(3) GQ(4) GQ(5) GQ(6) GQ(7)
        ACC(0) ACC(1) ACC(2) ACC(3) ACC(4) ACC(5) ACC(6) ACC(7)
    }
    if (e < eL) {   // predicated 8-batch covers remainder 1..7 in ONE round
        int last = eL - 1;
        LDP(0) LDP(1) LDP(2) LDP(3) LDP(4) LDP(5) LDP(6) LDP(7)
        GQ(0) GQ(1) GQ(2) GQ(3) GQ(4) GQ(5) GQ(6) GQ(7)
        ACC(0) ACC(1) ACC(2) ACC(3) ACC(4) ACC(5) ACC(6) ACC(7)
        e = eL;
    }
    // rare spill: block had >G_STAGE edges; finish from global
    for (; e < end; ++e) {
        Edge E0; { u32x2 q_ = ldnt((const u32x2*)(evg + e));
                   E0.c = (int)q_.x; E0.v = __uint_as_float(q_.y); }
        float fv0 = E0.v;
        GQ(0) ACC(0)
    }
#undef LDE
#undef LDP
#undef GQ
#undef ACC

    size_t o = ((size_t)row << 7) + ((size_t)h << 6) + (size_t)lane * 8;
    if (MODE == 1) {
        unsigned int m = mask2[(size_t)row * 16 + (h << 3) + lane];
        const float s = 1.0f / 0.9f;
        u16x8 gg;
        gg[0] = (m & 1u)   ? f2h(a0 * s) : (ushort)0;
        gg[1] = (m & 2u)   ? f2h(a1 * s) : (ushort)0;
        gg[2] = (m & 4u)   ? f2h(a2 * s) : (ushort)0;
        gg[3] = (m & 8u)   ? f2h(a3 * s) : (ushort)0;
        gg[4] = (m & 16u)  ? f2h(a4 * s) : (ushort)0;
        gg[5] = (m & 32u)  ? f2h(a5 * s) : (ushort)0;
        gg[6] = (m & 64u)  ? f2h(a6 * s) : (ushort)0;
        gg[7] = (m & 128u) ? f2h(a7 * s) : (ushort)0;
        stnt((u16x8*)(g2 + o), gg);
        u16x8 pp;
        pp[0] = f2h(a0); pp[1] = f2h(a1); pp[2] = f2h(a2); pp[3] = f2h(a3);
        pp[4] = f2h(a4); pp[5] = f2h(a5); pp[6] = f2h(a6); pp[7] = f2h(a7);
        stnt((u16x8*)(p16out + o), pp);
    } else {
        u32x4 eq = ldnt((const u32x4*)(emb16 + o));
        u32x4 pq = ldnt((const u32x4*)(p16in + o));
        float2 e0 = up2(eq.x), e1 = up2(eq.y), e2 = up2(eq.z), e3 = up2(eq.w);
        float2 p0 = up2(pq.x), p1 = up2(pq.y), p2 = up2(pq.z), p3 = up2(pq.w);
        const float t3 = 1.0f / 3.0f;
        f32x4 rA, rB;
        rA.x = (e0.x + p0.x + a0) * t3;
        rA.y = (e0.y + p0.y + a1) * t3;
        rA.z = (e1.x + p1.x + a2) * t3;
        rA.w = (e1.y + p1.y + a3) * t3;
        rB.x = (e2.x + p2.x + a4) * t3;
        rB.y = (e2.y + p2.y + a5) * t3;
        rB.z = (e3.x + p3.x + a6) * t3;
        rB.w = (e3.y + p3.y + a7) * t3;
        stnt((f32x4*)(out + o), rA);
        stnt((f32x4*)(out + o) + 1, rB);
    }
}

// ---- launch -------------------------------------------------------------

extern "C" void kernel_launch(void* const* d_in, const int* in_sizes, int n_in,
                              void* d_out, int out_size, void* d_ws, size_t ws_size,
                              hipStream_t stream) {
    const int* rows = (const int*)d_in[1];
    const int* cols = (const int*)d_in[2];
    const float* vals = (const float*)d_in[3];
    const float* emb = (const float*)d_in[4];
    const float* u1 = (const float*)d_in[5];
    const float* u2 = (const float*)d_in[6];
    float* out = (float*)d_out;

    const int N = in_sizes[0];
    const int E = in_sizes[1];
    const size_t ND = (size_t)N * DD;
    const int NW = (N + 1) / 2;          // packed counter words

    // workspace layout (~121 MB)
    char* ws = (char*)d_ws;
    Edge* ev     = (Edge*)ws;   ws += (size_t)E * sizeof(Edge);        // 12.8MB
    ushort* g1   = (ushort*)ws; ws += ND * sizeof(ushort);             // 25.6MB fp16
    ushort* g2   = (ushort*)ws; ws += ND * sizeof(ushort);             // 25.6MB fp16
    ushort* p16  = (ushort*)ws; ws += ND * sizeof(ushort);             // 25.6MB fp16 h1
    ushort* emb16= (ushort*)ws; ws += ND * sizeof(ushort);             // 25.6MB fp16 emb
    unsigned int* cnt16 = (unsigned int*)ws; ws += (size_t)NW * 4;     // 200KB packed
    int* rs      = (int*)ws;    ws += (size_t)N * sizeof(int);         // 0.4MB rowstart
    ushort* rank = (ushort*)ws; ws += (size_t)E * sizeof(ushort);      // 3.2MB
    int* bsum    = (int*)ws;    ws += 4096;
    unsigned char* mask2 = (unsigned char*)ws;                         // 1.6MB

    const int total8 = (int)(ND / 8);
    const int prepBlocks = (total8 + 255) / 256;
    const int gridE = (E + 255) / 256;
    const int gridFuse = prepBlocks > gridE ? prepBlocks : gridE;
    const int nScanBlocks = (N + SCAN_CHUNK - 1) / SCAN_CHUNK;
    const int gridRowX = (N + G_ROWS - 1) / G_ROWS;
    dim3 gridRow(gridRowX, 2, 1);

    hipMemsetAsync(cnt16, 0, (size_t)NW * 4, stream);
    // g1 stream + packed-16b hist (thread-level fusion)
    k_g1hist<<<gridFuse, 256, 0, stream>>>(emb, u1, g1, rows, cnt16, rank,
                                           total8, E);
    k_scan1<<<nScanBlocks, 256, 0, stream>>>(cnt16, rs, bsum, N);
    k_scan23<<<(N + 255) / 256, 256, 0, stream>>>(rs, bsum, nScanBlocks, N);
    // 1-edge/thread scatter + emb16/mask2 stream (thread-level fusion)
    k_scatter_prep<<<gridFuse, 256, 0, stream>>>(rows, cols, vals, rs, rank,
                                                 ev, emb, u2, emb16, mask2,
                                                 E, total8);
    // h1 = A*g1; p16 = fp16(h1); g2 = fp16(dropout(h1, mask2))
    k_gather<1><<<gridRow, 256, 0, stream>>>(rs, ev, g1, mask2, nullptr, nullptr,
                                             p16, g2, nullptr, N, E);
    // out = (emb16 + p16 + A*g2)/3
    k_gather<2><<<gridRow, 256, 0, stream>>>(rs, ev, g2, nullptr, emb16, p16,
                                             nullptr, nullptr, out, N, E);
}